// Round 1
// baseline (330.025 us; speedup 1.0000x reference)
//
#include <hip/hip_runtime.h>

#define HH 480
#define WW 640
#define BB 16
constexpr int HW = HH * WW;            // 307200
constexpr int BLK = 256;
constexpr int BLOCKS_PER_IMG = HW / BLK; // 1200

// Per-(dir,batch) coefficients: 16 floats
//  [0..2]  a   : z-row of (M @ Ki), M = R_dst @ R_src^T   (for d1)
//  [3]     cz  : t_dst.z - (M @ t_src).z
//  [4..12] P   : M^T @ Ki   (for uv0 field of dst frame reprojected to src)
//  [13..15] e  : t_src - M^T @ t_dst
__global__ void precompute_coeffs(const float* __restrict__ R0, const float* __restrict__ t0,
                                  const float* __restrict__ R1, const float* __restrict__ t1,
                                  const float* __restrict__ Ki, float* __restrict__ coeff) {
    int tid = threadIdx.x;
    if (tid >= 2 * BB) return;
    int dir = tid >> 4;
    int b = tid & 15;
    const float* Rs = (dir ? R1 : R0) + b * 9;
    const float* Ts = (dir ? t1 : t0) + b * 3;
    const float* Rd = (dir ? R0 : R1) + b * 9;
    const float* Td = (dir ? t0 : t1) + b * 3;

    float M[3][3];
    for (int i = 0; i < 3; i++)
        for (int j = 0; j < 3; j++)
            M[i][j] = Rd[i*3+0]*Rs[j*3+0] + Rd[i*3+1]*Rs[j*3+1] + Rd[i*3+2]*Rs[j*3+2];

    float a[3];
    for (int j = 0; j < 3; j++)
        a[j] = M[2][0]*Ki[0+j] + M[2][1]*Ki[3+j] + M[2][2]*Ki[6+j];
    float cz = Td[2] - (M[2][0]*Ts[0] + M[2][1]*Ts[1] + M[2][2]*Ts[2]);

    float P[9], e[3];
    for (int i = 0; i < 3; i++)
        for (int j = 0; j < 3; j++)
            P[i*3+j] = M[0][i]*Ki[0+j] + M[1][i]*Ki[3+j] + M[2][i]*Ki[6+j];
    for (int i = 0; i < 3; i++)
        e[i] = Ts[i] - (M[0][i]*Td[0] + M[1][i]*Td[1] + M[2][i]*Td[2]);

    float* o = coeff + tid * 16;
    o[0]=a[0]; o[1]=a[1]; o[2]=a[2]; o[3]=cz;
    #pragma unroll
    for (int i = 0; i < 9; i++) o[4+i] = P[i];
    o[13]=e[0]; o[14]=e[1]; o[15]=e[2];
}

__launch_bounds__(BLK)
__global__ void loss_kernel(const float* __restrict__ depth0, const float* __restrict__ depth1,
                            const float* __restrict__ flow0,  const float* __restrict__ flow1,
                            const float* __restrict__ amb0,   const float* __restrict__ amb1,
                            const float* __restrict__ pd0,    const float* __restrict__ pd1,
                            const float* __restrict__ K,
                            const float* __restrict__ coeff,
                            float2* __restrict__ partial) {
    const int dir = blockIdx.z;
    const int b = blockIdx.y;
    const int pix = blockIdx.x * BLK + threadIdx.x;

    const float* sD = (dir ? depth1 : depth0) + b * HW;
    const float* dD = (dir ? depth0 : depth1) + b * HW;
    const float* sF = (dir ? flow1  : flow0 ) + b * 2 * HW;
    const float* dF = (dir ? flow0  : flow1 ) + b * 2 * HW;
    const float* sA = (dir ? amb1   : amb0  ) + b * HW;
    const float* dA = (dir ? amb0   : amb1  ) + b * HW;
    const float* dP = (dir ? pd0    : pd1   ) + b * HW;

    const float* cf = coeff + (dir * BB + b) * 16;
    const float a0=cf[0], a1=cf[1], a2=cf[2], cz=cf[3];
    const float P00=cf[4], P01=cf[5], P02=cf[6];
    const float P10=cf[7], P11=cf[8], P12=cf[9];
    const float P20=cf[10], P21=cf[11], P22=cf[12];
    const float e0=cf[13], e1=cf[14], e2=cf[15];
    const float K00=K[0], K01=K[1], K02=K[2], K10=K[3], K11=K[4], K12=K[5];

    const int px = pix % WW, py = pix / WW;
    const float fpx = (float)px, fpy = (float)py;

    const float dep = sD[pix];
    const float fx = sF[pix], fy = sF[HW + pix];
    const float av = sA[pix];

    // d1 = depth * (M@Ki @ [x,y,1]).z + (t_dst - M t_src).z
    const float d1 = dep * (a0 * fpx + a1 * fpy + a2) + cz;

    // sample coords: exactly x+fx, y+fy (normalize/denormalize cancels)
    const float xs = fpx + fx, ys = fpy + fy;
    const float x0f = floorf(xs), y0f = floorf(ys);
    const float wx1 = xs - x0f, wy1 = ys - y0f;
    const int x0 = (int)x0f, y0 = (int)y0f;

    float s_d = 0.f, s_fx = 0.f, s_fy = 0.f, s_a = 0.f, s_u = 0.f, s_v = 0.f;
    #pragma unroll
    for (int cy2 = 0; cy2 < 2; cy2++) {
        const int yi = y0 + cy2;
        const bool vy = (yi >= 0) && (yi < HH);
        const float wy = cy2 ? wy1 : 1.f - wy1;
        const int yc = min(max(yi, 0), HH - 1);
        #pragma unroll
        for (int cx2 = 0; cx2 < 2; cx2++) {
            const int xi = x0 + cx2;
            const bool vx = (xi >= 0) && (xi < WW);
            const float w = ((vx && vy) ? 1.f : 0.f) * wy * (cx2 ? wx1 : 1.f - wx1);
            const int xc = min(max(xi, 0), WW - 1);
            const int idx = yc * WW + xc;
            const float dd  = dD[idx];
            const float ffx = dF[idx], ffy = dF[HW + idx];
            const float aa  = dA[idx];
            const float pdv = dP[idx];
            // uv0 at integer corner (xi, yi) of dst frame, on the fly
            const float fxi = (float)xi, fyi = (float)yi;
            const float rx = pdv * (P00 * fxi + P01 * fyi + P02) + e0;
            const float ry = pdv * (P10 * fxi + P11 * fyi + P12) + e1;
            const float rz = pdv * (P20 * fxi + P21 * fyi + P22) + e2;
            const float invd = 1.f / (fmaxf(rz, 0.f) + 1e-12f);
            const float uu = (K00 * rx + K01 * ry + K02 * rz) * invd;
            const float vv = (K10 * rx + K11 * ry + K12 * rz) * invd;
            s_d  = fmaf(w, dd,  s_d);
            s_fx = fmaf(w, ffx, s_fx);
            s_fy = fmaf(w, ffy, s_fy);
            s_a  = fmaf(w, aa,  s_a);
            s_u  = fmaf(w, uu,  s_u);
            s_v  = fmaf(w, vv,  s_v);
        }
    }

    const float diff = fabsf(d1 - s_d);
    const float sfx = fx + s_fx, sfy = fy + s_fy;
    const bool fb = (sfx * sfx + sfy * sfy) <
                    (0.5f + 0.02f * ((fx * fx + fy * fy) + (s_fx * s_fx + s_fy * s_fy)));
    const bool vc = fabsf(av - s_a) < 0.01f;
    const float du = s_u - fpx, dv = s_v - fpy;
    const bool rf = (du * du + dv * dv) < 1.f;
    const float m = (fb && vc && rf) ? 1.f : 0.f;
    float num = diff * m;
    float den = m;

    #pragma unroll
    for (int off = 32; off > 0; off >>= 1) {
        num += __shfl_down(num, off);
        den += __shfl_down(den, off);
    }
    __shared__ float red[8];
    const int wave = threadIdx.x >> 6, lane = threadIdx.x & 63;
    if (lane == 0) { red[wave] = num; red[4 + wave] = den; }
    __syncthreads();
    if (threadIdx.x == 0) {
        float n = red[0] + red[1] + red[2] + red[3];
        float d = red[4] + red[5] + red[6] + red[7];
        partial[(dir * BB + b) * BLOCKS_PER_IMG + blockIdx.x] = make_float2(n, d);
    }
}

__global__ void finalize_kernel(const float2* __restrict__ partial, float* __restrict__ out) {
    const int NPB = BB * BLOCKS_PER_IMG; // 19200 per direction
    double n0 = 0, d0 = 0, n1 = 0, d1 = 0;
    for (int i = threadIdx.x; i < NPB; i += 256) {
        float2 p = partial[i];        n0 += p.x; d0 += p.y;
        float2 q = partial[NPB + i];  n1 += q.x; d1 += q.y;
    }
    #pragma unroll
    for (int off = 32; off > 0; off >>= 1) {
        n0 += __shfl_down(n0, off); d0 += __shfl_down(d0, off);
        n1 += __shfl_down(n1, off); d1 += __shfl_down(d1, off);
    }
    __shared__ double red[16];
    int wave = threadIdx.x >> 6, lane = threadIdx.x & 63;
    if (lane == 0) { red[wave] = n0; red[4+wave] = d0; red[8+wave] = n1; red[12+wave] = d1; }
    __syncthreads();
    if (threadIdx.x == 0) {
        double N0 = red[0]+red[1]+red[2]+red[3];
        double D0 = red[4]+red[5]+red[6]+red[7];
        double N1 = red[8]+red[9]+red[10]+red[11];
        double D1 = red[12]+red[13]+red[14]+red[15];
        out[0] = (float)(N0 / (D0 + 1e-8) + N1 / (D1 + 1e-8));
    }
}

extern "C" void kernel_launch(void* const* d_in, const int* in_sizes, int n_in,
                              void* d_out, int out_size, void* d_ws, size_t ws_size,
                              hipStream_t stream) {
    const float* depth0 = (const float*)d_in[0];
    const float* depth1 = (const float*)d_in[1];
    const float* R0     = (const float*)d_in[2];
    const float* t0     = (const float*)d_in[3];
    const float* R1     = (const float*)d_in[4];
    const float* t1     = (const float*)d_in[5];
    const float* flow0  = (const float*)d_in[6];
    const float* flow1  = (const float*)d_in[7];
    const float* amb0   = (const float*)d_in[8];
    const float* amb1   = (const float*)d_in[9];
    const float* pd0    = (const float*)d_in[10];
    const float* pd1    = (const float*)d_in[11];
    const float* K      = (const float*)d_in[12];
    const float* Ki     = (const float*)d_in[13];

    float*  coeff   = (float*)d_ws;                     // 2*16*16 floats = 2 KB
    float2* partial = (float2*)((char*)d_ws + 2048);    // 2*19200 float2 = 300 KB

    precompute_coeffs<<<1, 64, 0, stream>>>(R0, t0, R1, t1, Ki, coeff);
    dim3 grid(BLOCKS_PER_IMG, BB, 2);
    loss_kernel<<<grid, BLK, 0, stream>>>(depth0, depth1, flow0, flow1, amb0, amb1,
                                          pd0, pd1, K, coeff, partial);
    finalize_kernel<<<1, 256, 0, stream>>>(partial, (float*)d_out);
}

// Round 2
// 199.231 us; speedup vs baseline: 1.6565x; 1.6565x over previous
//
#include <hip/hip_runtime.h>

#define HH 480
#define WW 640
#define BB 16
constexpr int HW = HH * WW;              // 307200
constexpr int BLK = 256;
constexpr int BLOCKS_PER_IMG = HW / BLK; // 1200

// Per-(dir,batch) coefficients: 16 floats
//  [0..2]  a   : z-row of (M @ Ki), M = R_dst @ R_src^T   (for d1)
//  [3]     cz  : t_dst.z - (M @ t_src).z
//  [4..12] P   : M^T @ Ki   (for uv0 field of dst frame reprojected to src)
//  [13..15] e  : t_src - M^T @ t_dst
__global__ void precompute_coeffs(const float* __restrict__ R0, const float* __restrict__ t0,
                                  const float* __restrict__ R1, const float* __restrict__ t1,
                                  const float* __restrict__ Ki, float* __restrict__ coeff) {
    int tid = threadIdx.x;
    if (tid >= 2 * BB) return;
    int dir = tid >> 4;
    int b = tid & 15;
    const float* Rs = (dir ? R1 : R0) + b * 9;
    const float* Ts = (dir ? t1 : t0) + b * 3;
    const float* Rd = (dir ? R0 : R1) + b * 9;
    const float* Td = (dir ? t0 : t1) + b * 3;

    float M[3][3];
    for (int i = 0; i < 3; i++)
        for (int j = 0; j < 3; j++)
            M[i][j] = Rd[i*3+0]*Rs[j*3+0] + Rd[i*3+1]*Rs[j*3+1] + Rd[i*3+2]*Rs[j*3+2];

    float a[3];
    for (int j = 0; j < 3; j++)
        a[j] = M[2][0]*Ki[0+j] + M[2][1]*Ki[3+j] + M[2][2]*Ki[6+j];
    float cz = Td[2] - (M[2][0]*Ts[0] + M[2][1]*Ts[1] + M[2][2]*Ts[2]);

    float P[9], e[3];
    for (int i = 0; i < 3; i++)
        for (int j = 0; j < 3; j++)
            P[i*3+j] = M[0][i]*Ki[0+j] + M[1][i]*Ki[3+j] + M[2][i]*Ki[6+j];
    for (int i = 0; i < 3; i++)
        e[i] = Ts[i] - (M[0][i]*Td[0] + M[1][i]*Td[1] + M[2][i]*Td[2]);

    float* o = coeff + tid * 16;
    o[0]=a[0]; o[1]=a[1]; o[2]=a[2]; o[3]=cz;
    #pragma unroll
    for (int i = 0; i < 9; i++) o[4+i] = P[i];
    o[13]=e[0]; o[14]=e[1]; o[15]=e[2];
}

// Pack (depth, flow_x, flow_y, amb) of each frame into a float4 image.
__launch_bounds__(BLK)
__global__ void pack_kernel(const float* __restrict__ depth0, const float* __restrict__ flow0,
                            const float* __restrict__ amb0,
                            const float* __restrict__ depth1, const float* __restrict__ flow1,
                            const float* __restrict__ amb1,
                            float4* __restrict__ packed) {
    const int f = blockIdx.z, b = blockIdx.y;
    const int pix = blockIdx.x * BLK + threadIdx.x;
    const float* D = (f ? depth1 : depth0) + b * HW;
    const float* F = (f ? flow1  : flow0 ) + b * 2 * HW;
    const float* A = (f ? amb1   : amb0  ) + b * HW;
    packed[(size_t)(f * BB + b) * HW + pix] =
        make_float4(D[pix], F[pix], F[HW + pix], A[pix]);
}

// 2D-tiled fused loss: wave covers 16x4 pixels, block covers 32x8.
__launch_bounds__(BLK)
__global__ void loss_kernel_packed(const float4* __restrict__ packed,
                                   const float* __restrict__ pd0, const float* __restrict__ pd1,
                                   const float* __restrict__ K,
                                   const float* __restrict__ coeff,
                                   float2* __restrict__ partial) {
    const int dir = blockIdx.z;
    const int b = blockIdx.y;
    const int tile_x = blockIdx.x % (WW / 32);
    const int tile_y = blockIdx.x / (WW / 32);
    const int lane = threadIdx.x & 63, wv = threadIdx.x >> 6;
    const int px = tile_x * 32 + (wv & 1) * 16 + (lane & 15);
    const int py = tile_y * 8 + (wv >> 1) * 4 + (lane >> 4);
    const int pix = py * WW + px;

    const float4* sP = packed + (size_t)(dir * BB + b) * HW;        // src frame = dir
    const float4* dP4 = packed + (size_t)((dir ^ 1) * BB + b) * HW; // dst frame
    const float* dPd = (dir ? pd0 : pd1) + b * HW;

    const float* cf = coeff + (dir * BB + b) * 16;
    const float a0=cf[0], a1=cf[1], a2=cf[2], cz=cf[3];
    const float P00=cf[4], P01=cf[5], P02=cf[6];
    const float P10=cf[7], P11=cf[8], P12=cf[9];
    const float P20=cf[10], P21=cf[11], P22=cf[12];
    const float e0=cf[13], e1=cf[14], e2=cf[15];
    const float K00=K[0], K01=K[1], K02=K[2], K10=K[3], K11=K[4], K12=K[5];

    const float fpx = (float)px, fpy = (float)py;

    const float4 sv = sP[pix];
    const float dep = sv.x, fx = sv.y, fy = sv.z, av = sv.w;

    const float d1 = dep * (a0 * fpx + a1 * fpy + a2) + cz;

    const float xs = fpx + fx, ys = fpy + fy;
    const float x0f = floorf(xs), y0f = floorf(ys);
    const float wx1 = xs - x0f, wy1 = ys - y0f;
    const int x0 = (int)x0f, y0 = (int)y0f;

    float s_d = 0.f, s_fx = 0.f, s_fy = 0.f, s_a = 0.f, s_u = 0.f, s_v = 0.f;
    #pragma unroll
    for (int cy2 = 0; cy2 < 2; cy2++) {
        const int yi = y0 + cy2;
        const bool vy = (yi >= 0) && (yi < HH);
        const float wy = cy2 ? wy1 : 1.f - wy1;
        const int yc = min(max(yi, 0), HH - 1);
        #pragma unroll
        for (int cx2 = 0; cx2 < 2; cx2++) {
            const int xi = x0 + cx2;
            const bool vx = (xi >= 0) && (xi < WW);
            const float w = ((vx && vy) ? 1.f : 0.f) * wy * (cx2 ? wx1 : 1.f - wx1);
            const int xc = min(max(xi, 0), WW - 1);
            const int idx = yc * WW + xc;
            const float4 c = dP4[idx];
            const float pdv = dPd[idx];
            const float fxi = (float)xi, fyi = (float)yi;
            const float rx = pdv * (P00 * fxi + P01 * fyi + P02) + e0;
            const float ry = pdv * (P10 * fxi + P11 * fyi + P12) + e1;
            const float rz = pdv * (P20 * fxi + P21 * fyi + P22) + e2;
            const float invd = 1.f / (fmaxf(rz, 0.f) + 1e-12f);
            const float uu = (K00 * rx + K01 * ry + K02 * rz) * invd;
            const float vv = (K10 * rx + K11 * ry + K12 * rz) * invd;
            s_d  = fmaf(w, c.x, s_d);
            s_fx = fmaf(w, c.y, s_fx);
            s_fy = fmaf(w, c.z, s_fy);
            s_a  = fmaf(w, c.w, s_a);
            s_u  = fmaf(w, uu,  s_u);
            s_v  = fmaf(w, vv,  s_v);
        }
    }

    const float diff = fabsf(d1 - s_d);
    const float sfx = fx + s_fx, sfy = fy + s_fy;
    const bool fb = (sfx * sfx + sfy * sfy) <
                    (0.5f + 0.02f * ((fx * fx + fy * fy) + (s_fx * s_fx + s_fy * s_fy)));
    const bool vc = fabsf(av - s_a) < 0.01f;
    const float du = s_u - fpx, dv = s_v - fpy;
    const bool rf = (du * du + dv * dv) < 1.f;
    const float m = (fb && vc && rf) ? 1.f : 0.f;
    float num = diff * m;
    float den = m;

    #pragma unroll
    for (int off = 32; off > 0; off >>= 1) {
        num += __shfl_down(num, off);
        den += __shfl_down(den, off);
    }
    __shared__ float red[8];
    if ((threadIdx.x & 63) == 0) { red[wv] = num; red[4 + wv] = den; }
    __syncthreads();
    if (threadIdx.x == 0) {
        float n = red[0] + red[1] + red[2] + red[3];
        float d = red[4] + red[5] + red[6] + red[7];
        partial[(dir * BB + b) * BLOCKS_PER_IMG + blockIdx.x] = make_float2(n, d);
    }
}

// ---------- fallback (round-1) 1D kernel, used if ws too small ----------
__launch_bounds__(BLK)
__global__ void loss_kernel(const float* __restrict__ depth0, const float* __restrict__ depth1,
                            const float* __restrict__ flow0,  const float* __restrict__ flow1,
                            const float* __restrict__ amb0,   const float* __restrict__ amb1,
                            const float* __restrict__ pd0,    const float* __restrict__ pd1,
                            const float* __restrict__ K,
                            const float* __restrict__ coeff,
                            float2* __restrict__ partial) {
    const int dir = blockIdx.z;
    const int b = blockIdx.y;
    const int pix = blockIdx.x * BLK + threadIdx.x;

    const float* sD = (dir ? depth1 : depth0) + b * HW;
    const float* dD = (dir ? depth0 : depth1) + b * HW;
    const float* sF = (dir ? flow1  : flow0 ) + b * 2 * HW;
    const float* dF = (dir ? flow0  : flow1 ) + b * 2 * HW;
    const float* sA = (dir ? amb1   : amb0  ) + b * HW;
    const float* dA = (dir ? amb0   : amb1  ) + b * HW;
    const float* dP = (dir ? pd0    : pd1   ) + b * HW;

    const float* cf = coeff + (dir * BB + b) * 16;
    const float a0=cf[0], a1=cf[1], a2=cf[2], cz=cf[3];
    const float P00=cf[4], P01=cf[5], P02=cf[6];
    const float P10=cf[7], P11=cf[8], P12=cf[9];
    const float P20=cf[10], P21=cf[11], P22=cf[12];
    const float e0=cf[13], e1=cf[14], e2=cf[15];
    const float K00=K[0], K01=K[1], K02=K[2], K10=K[3], K11=K[4], K12=K[5];

    const int px = pix % WW, py = pix / WW;
    const float fpx = (float)px, fpy = (float)py;

    const float dep = sD[pix];
    const float fx = sF[pix], fy = sF[HW + pix];
    const float av = sA[pix];
    const float d1 = dep * (a0 * fpx + a1 * fpy + a2) + cz;

    const float xs = fpx + fx, ys = fpy + fy;
    const float x0f = floorf(xs), y0f = floorf(ys);
    const float wx1 = xs - x0f, wy1 = ys - y0f;
    const int x0 = (int)x0f, y0 = (int)y0f;

    float s_d = 0.f, s_fx = 0.f, s_fy = 0.f, s_a = 0.f, s_u = 0.f, s_v = 0.f;
    #pragma unroll
    for (int cy2 = 0; cy2 < 2; cy2++) {
        const int yi = y0 + cy2;
        const bool vy = (yi >= 0) && (yi < HH);
        const float wy = cy2 ? wy1 : 1.f - wy1;
        const int yc = min(max(yi, 0), HH - 1);
        #pragma unroll
        for (int cx2 = 0; cx2 < 2; cx2++) {
            const int xi = x0 + cx2;
            const bool vx = (xi >= 0) && (xi < WW);
            const float w = ((vx && vy) ? 1.f : 0.f) * wy * (cx2 ? wx1 : 1.f - wx1);
            const int xc = min(max(xi, 0), WW - 1);
            const int idx = yc * WW + xc;
            const float dd  = dD[idx];
            const float ffx = dF[idx], ffy = dF[HW + idx];
            const float aa  = dA[idx];
            const float pdv = dP[idx];
            const float fxi = (float)xi, fyi = (float)yi;
            const float rx = pdv * (P00 * fxi + P01 * fyi + P02) + e0;
            const float ry = pdv * (P10 * fxi + P11 * fyi + P12) + e1;
            const float rz = pdv * (P20 * fxi + P21 * fyi + P22) + e2;
            const float invd = 1.f / (fmaxf(rz, 0.f) + 1e-12f);
            const float uu = (K00 * rx + K01 * ry + K02 * rz) * invd;
            const float vv = (K10 * rx + K11 * ry + K12 * rz) * invd;
            s_d  = fmaf(w, dd,  s_d);
            s_fx = fmaf(w, ffx, s_fx);
            s_fy = fmaf(w, ffy, s_fy);
            s_a  = fmaf(w, aa,  s_a);
            s_u  = fmaf(w, uu,  s_u);
            s_v  = fmaf(w, vv,  s_v);
        }
    }

    const float diff = fabsf(d1 - s_d);
    const float sfx = fx + s_fx, sfy = fy + s_fy;
    const bool fb = (sfx * sfx + sfy * sfy) <
                    (0.5f + 0.02f * ((fx * fx + fy * fy) + (s_fx * s_fx + s_fy * s_fy)));
    const bool vc = fabsf(av - s_a) < 0.01f;
    const float du = s_u - fpx, dv = s_v - fpy;
    const bool rf = (du * du + dv * dv) < 1.f;
    const float m = (fb && vc && rf) ? 1.f : 0.f;
    float num = diff * m;
    float den = m;

    #pragma unroll
    for (int off = 32; off > 0; off >>= 1) {
        num += __shfl_down(num, off);
        den += __shfl_down(den, off);
    }
    __shared__ float red[8];
    const int wave = threadIdx.x >> 6, lane = threadIdx.x & 63;
    if (lane == 0) { red[wave] = num; red[4 + wave] = den; }
    __syncthreads();
    if (threadIdx.x == 0) {
        float n = red[0] + red[1] + red[2] + red[3];
        float d = red[4] + red[5] + red[6] + red[7];
        partial[(dir * BB + b) * BLOCKS_PER_IMG + blockIdx.x] = make_float2(n, d);
    }
}

__global__ void finalize_kernel(const float2* __restrict__ partial, float* __restrict__ out) {
    const int NPB = BB * BLOCKS_PER_IMG; // 19200 per direction
    double n0 = 0, d0 = 0, n1 = 0, d1 = 0;
    for (int i = threadIdx.x; i < NPB; i += 256) {
        float2 p = partial[i];        n0 += p.x; d0 += p.y;
        float2 q = partial[NPB + i];  n1 += q.x; d1 += q.y;
    }
    #pragma unroll
    for (int off = 32; off > 0; off >>= 1) {
        n0 += __shfl_down(n0, off); d0 += __shfl_down(d0, off);
        n1 += __shfl_down(n1, off); d1 += __shfl_down(d1, off);
    }
    __shared__ double red[16];
    int wave = threadIdx.x >> 6, lane = threadIdx.x & 63;
    if (lane == 0) { red[wave] = n0; red[4+wave] = d0; red[8+wave] = n1; red[12+wave] = d1; }
    __syncthreads();
    if (threadIdx.x == 0) {
        double N0 = red[0]+red[1]+red[2]+red[3];
        double D0 = red[4]+red[5]+red[6]+red[7];
        double N1 = red[8]+red[9]+red[10]+red[11];
        double D1 = red[12]+red[13]+red[14]+red[15];
        out[0] = (float)(N0 / (D0 + 1e-8) + N1 / (D1 + 1e-8));
    }
}

extern "C" void kernel_launch(void* const* d_in, const int* in_sizes, int n_in,
                              void* d_out, int out_size, void* d_ws, size_t ws_size,
                              hipStream_t stream) {
    const float* depth0 = (const float*)d_in[0];
    const float* depth1 = (const float*)d_in[1];
    const float* R0     = (const float*)d_in[2];
    const float* t0     = (const float*)d_in[3];
    const float* R1     = (const float*)d_in[4];
    const float* t1     = (const float*)d_in[5];
    const float* flow0  = (const float*)d_in[6];
    const float* flow1  = (const float*)d_in[7];
    const float* amb0   = (const float*)d_in[8];
    const float* amb1   = (const float*)d_in[9];
    const float* pd0    = (const float*)d_in[10];
    const float* pd1    = (const float*)d_in[11];
    const float* K      = (const float*)d_in[12];
    const float* Ki     = (const float*)d_in[13];

    float*  coeff   = (float*)d_ws;                     // 2 KB
    float2* partial = (float2*)((char*)d_ws + 2048);    // 2*19200 float2 = 300 KB
    const size_t packed_off = 512 * 1024;
    const size_t packed_bytes = (size_t)2 * BB * HW * sizeof(float4); // 157.3 MB
    float4* packed = (float4*)((char*)d_ws + packed_off);

    precompute_coeffs<<<1, 64, 0, stream>>>(R0, t0, R1, t1, Ki, coeff);
    dim3 grid(BLOCKS_PER_IMG, BB, 2);

    if (ws_size >= packed_off + packed_bytes) {
        pack_kernel<<<grid, BLK, 0, stream>>>(depth0, flow0, amb0, depth1, flow1, amb1, packed);
        loss_kernel_packed<<<grid, BLK, 0, stream>>>(packed, pd0, pd1, K, coeff, partial);
    } else {
        loss_kernel<<<grid, BLK, 0, stream>>>(depth0, depth1, flow0, flow1, amb0, amb1,
                                              pd0, pd1, K, coeff, partial);
    }
    finalize_kernel<<<1, 256, 0, stream>>>(partial, (float*)d_out);
}

// Round 3
// 195.718 us; speedup vs baseline: 1.6862x; 1.0179x over previous
//
#include <hip/hip_runtime.h>

#define HH 480
#define WW 640
#define BB 16
constexpr int HW = HH * WW;          // 307200
constexpr int TW = 32, TH = 16;      // output tile per block
constexpr int HALO = 10;
constexpr int RW = TW + 2 * HALO;    // 52
constexpr int RH = TH + 2 * HALO;    // 36
constexpr int RN = RW * RH;          // 1872
constexpr int TPB = 512;             // 8 waves
constexpr int TILES_X = WW / TW;     // 20
constexpr int TILES_Y = HH / TH;     // 30
constexpr int TILES = TILES_X * TILES_Y; // 600

// Per-(dir,batch) coefficients: 16 floats
//  [0..2]  a   : z-row of (M @ Ki), M = R_dst @ R_src^T   (for d1)
//  [3]     cz  : t_dst.z - (M @ t_src).z
//  [4..12] P   : M^T @ Ki   (for uv0 field of dst frame reprojected to src)
//  [13..15] e  : t_src - M^T @ t_dst
__global__ void precompute_coeffs(const float* __restrict__ R0, const float* __restrict__ t0,
                                  const float* __restrict__ R1, const float* __restrict__ t1,
                                  const float* __restrict__ Ki, float* __restrict__ coeff) {
    int tid = threadIdx.x;
    if (tid >= 2 * BB) return;
    int dir = tid >> 4;
    int b = tid & 15;
    const float* Rs = (dir ? R1 : R0) + b * 9;
    const float* Ts = (dir ? t1 : t0) + b * 3;
    const float* Rd = (dir ? R0 : R1) + b * 9;
    const float* Td = (dir ? t0 : t1) + b * 3;

    float M[3][3];
    for (int i = 0; i < 3; i++)
        for (int j = 0; j < 3; j++)
            M[i][j] = Rd[i*3+0]*Rs[j*3+0] + Rd[i*3+1]*Rs[j*3+1] + Rd[i*3+2]*Rs[j*3+2];

    float a[3];
    for (int j = 0; j < 3; j++)
        a[j] = M[2][0]*Ki[0+j] + M[2][1]*Ki[3+j] + M[2][2]*Ki[6+j];
    float cz = Td[2] - (M[2][0]*Ts[0] + M[2][1]*Ts[1] + M[2][2]*Ts[2]);

    float P[9], e[3];
    for (int i = 0; i < 3; i++)
        for (int j = 0; j < 3; j++)
            P[i*3+j] = M[0][i]*Ki[0+j] + M[1][i]*Ki[3+j] + M[2][i]*Ki[6+j];
    for (int i = 0; i < 3; i++)
        e[i] = Ts[i] - (M[0][i]*Td[0] + M[1][i]*Td[1] + M[2][i]*Td[2]);

    float* o = coeff + tid * 16;
    o[0]=a[0]; o[1]=a[1]; o[2]=a[2]; o[3]=cz;
    #pragma unroll
    for (int i = 0; i < 9; i++) o[4+i] = P[i];
    o[13]=e[0]; o[14]=e[1]; o[15]=e[2];
}

__launch_bounds__(TPB)
__global__ void fused_loss(const float* __restrict__ depth0, const float* __restrict__ depth1,
                           const float* __restrict__ flow0,  const float* __restrict__ flow1,
                           const float* __restrict__ amb0,   const float* __restrict__ amb1,
                           const float* __restrict__ pd0,    const float* __restrict__ pd1,
                           const float* __restrict__ K,
                           const float* __restrict__ coeff,
                           float2* __restrict__ partial) {
    __shared__ float4 lds4[RN];   // dst (d, fx, fy, amb)
    __shared__ float  ldsp[RN];   // dst pd
    __shared__ float  red[16];

    const int dir = blockIdx.z;
    const int b = blockIdx.y;
    const int tile = blockIdx.x;
    const int tx = tile % TILES_X, ty = tile / TILES_X;
    const int gx0 = tx * TW - HALO, gy0 = ty * TH - HALO;
    const int tid = threadIdx.x;

    const float* sD = (dir ? depth1 : depth0) + b * HW;
    const float* dD = (dir ? depth0 : depth1) + b * HW;
    const float* sF = (dir ? flow1  : flow0 ) + b * 2 * HW;
    const float* dF = (dir ? flow0  : flow1 ) + b * 2 * HW;
    const float* sA = (dir ? amb1   : amb0  ) + b * HW;
    const float* dA = (dir ? amb0   : amb1  ) + b * HW;
    const float* dP = (dir ? pd0    : pd1   ) + b * HW;

    // ---- stage dst halo region into LDS (border-replicate clamp) ----
    #pragma unroll
    for (int i = 0; i < 4; i++) {
        const int idx = i * TPB + tid;
        if (idx < RN) {
            const int ly = idx / RW, lx = idx - ly * RW;
            const int gx = min(max(gx0 + lx, 0), WW - 1);
            const int gy = min(max(gy0 + ly, 0), HH - 1);
            const int g = gy * WW + gx;
            lds4[idx] = make_float4(dD[g], dF[g], dF[HW + g], dA[g]);
            ldsp[idx] = dP[g];
        }
    }
    __syncthreads();

    const float* cf = coeff + (dir * BB + b) * 16;
    const float a0=cf[0], a1=cf[1], a2=cf[2], cz=cf[3];
    const float P00=cf[4], P01=cf[5], P02=cf[6];
    const float P10=cf[7], P11=cf[8], P12=cf[9];
    const float P20=cf[10], P21=cf[11], P22=cf[12];
    const float e0=cf[13], e1=cf[14], e2=cf[15];
    const float K00=K[0], K01=K[1], K02=K[2], K10=K[3], K11=K[4], K12=K[5];

    const int px = tx * TW + (tid & 31);
    const int py = ty * TH + (tid >> 5);
    const int pix = py * WW + px;
    const float fpx = (float)px, fpy = (float)py;

    const float dep = sD[pix];
    const float fx = sF[pix], fy = sF[HW + pix];
    const float av = sA[pix];

    const float d1 = dep * (a0 * fpx + a1 * fpy + a2) + cz;

    // sample coords: exactly x+fx, y+fy (normalize/denormalize cancels)
    const float xs = fpx + fx, ys = fpy + fy;
    const float x0f = floorf(xs), y0f = floorf(ys);
    const float wx1 = xs - x0f, wy1 = ys - y0f;
    const int x0 = (int)x0f, y0 = (int)y0f;

    float s_d = 0.f, s_fx = 0.f, s_fy = 0.f, s_a = 0.f, s_u = 0.f, s_v = 0.f;
    #pragma unroll
    for (int cy2 = 0; cy2 < 2; cy2++) {
        const int yi = y0 + cy2;
        const float wy = cy2 ? wy1 : 1.f - wy1;
        #pragma unroll
        for (int cx2 = 0; cx2 < 2; cx2++) {
            const int xi = x0 + cx2;
            const bool valid = ((unsigned)xi < (unsigned)WW) && ((unsigned)yi < (unsigned)HH);
            const float w = valid ? wy * (cx2 ? wx1 : 1.f - wx1) : 0.f;
            float dd = 0.f, ffx = 0.f, ffy = 0.f, aa = 0.f, pdv = 0.f;
            if (valid) {
                const int lx = xi - gx0, ly = yi - gy0;
                if (((unsigned)lx < (unsigned)RW) && ((unsigned)ly < (unsigned)RH)) {
                    const int lidx = ly * RW + lx;
                    const float4 c = lds4[lidx];
                    dd = c.x; ffx = c.y; ffy = c.z; aa = c.w;
                    pdv = ldsp[lidx];
                } else {  // rare: flow beyond halo — exact global fallback
                    const int g = yi * WW + xi;
                    dd = dD[g]; ffx = dF[g]; ffy = dF[HW + g]; aa = dA[g]; pdv = dP[g];
                }
            }
            const float fxi = (float)xi, fyi = (float)yi;
            const float rx = pdv * (P00 * fxi + P01 * fyi + P02) + e0;
            const float ry = pdv * (P10 * fxi + P11 * fyi + P12) + e1;
            const float rz = pdv * (P20 * fxi + P21 * fyi + P22) + e2;
            const float invd = 1.f / (fmaxf(rz, 0.f) + 1e-12f);
            const float uu = (K00 * rx + K01 * ry + K02 * rz) * invd;
            const float vv = (K10 * rx + K11 * ry + K12 * rz) * invd;
            s_d  = fmaf(w, dd,  s_d);
            s_fx = fmaf(w, ffx, s_fx);
            s_fy = fmaf(w, ffy, s_fy);
            s_a  = fmaf(w, aa,  s_a);
            s_u  = fmaf(w, uu,  s_u);
            s_v  = fmaf(w, vv,  s_v);
        }
    }

    const float diff = fabsf(d1 - s_d);
    const float sfx = fx + s_fx, sfy = fy + s_fy;
    const bool fb = (sfx * sfx + sfy * sfy) <
                    (0.5f + 0.02f * ((fx * fx + fy * fy) + (s_fx * s_fx + s_fy * s_fy)));
    const bool vc = fabsf(av - s_a) < 0.01f;
    const float du = s_u - fpx, dv = s_v - fpy;
    const bool rf = (du * du + dv * dv) < 1.f;
    const float m = (fb && vc && rf) ? 1.f : 0.f;
    float num = diff * m;
    float den = m;

    #pragma unroll
    for (int off = 32; off > 0; off >>= 1) {
        num += __shfl_down(num, off);
        den += __shfl_down(den, off);
    }
    const int wv = tid >> 6;
    if ((tid & 63) == 0) { red[wv] = num; red[8 + wv] = den; }
    __syncthreads();
    if (tid == 0) {
        float n = 0.f, d = 0.f;
        #pragma unroll
        for (int i = 0; i < 8; i++) { n += red[i]; d += red[8 + i]; }
        partial[(dir * BB + b) * TILES + tile] = make_float2(n, d);
    }
}

__global__ void finalize_kernel(const float2* __restrict__ partial, float* __restrict__ out) {
    const int NPB = BB * TILES; // 9600 per direction
    double n0 = 0, d0 = 0, n1 = 0, d1 = 0;
    for (int i = threadIdx.x; i < NPB; i += 256) {
        float2 p = partial[i];        n0 += p.x; d0 += p.y;
        float2 q = partial[NPB + i];  n1 += q.x; d1 += q.y;
    }
    #pragma unroll
    for (int off = 32; off > 0; off >>= 1) {
        n0 += __shfl_down(n0, off); d0 += __shfl_down(d0, off);
        n1 += __shfl_down(n1, off); d1 += __shfl_down(d1, off);
    }
    __shared__ double red[16];
    int wave = threadIdx.x >> 6, lane = threadIdx.x & 63;
    if (lane == 0) { red[wave] = n0; red[4+wave] = d0; red[8+wave] = n1; red[12+wave] = d1; }
    __syncthreads();
    if (threadIdx.x == 0) {
        double N0 = red[0]+red[1]+red[2]+red[3];
        double D0 = red[4]+red[5]+red[6]+red[7];
        double N1 = red[8]+red[9]+red[10]+red[11];
        double D1 = red[12]+red[13]+red[14]+red[15];
        out[0] = (float)(N0 / (D0 + 1e-8) + N1 / (D1 + 1e-8));
    }
}

extern "C" void kernel_launch(void* const* d_in, const int* in_sizes, int n_in,
                              void* d_out, int out_size, void* d_ws, size_t ws_size,
                              hipStream_t stream) {
    const float* depth0 = (const float*)d_in[0];
    const float* depth1 = (const float*)d_in[1];
    const float* R0     = (const float*)d_in[2];
    const float* t0     = (const float*)d_in[3];
    const float* R1     = (const float*)d_in[4];
    const float* t1     = (const float*)d_in[5];
    const float* flow0  = (const float*)d_in[6];
    const float* flow1  = (const float*)d_in[7];
    const float* amb0   = (const float*)d_in[8];
    const float* amb1   = (const float*)d_in[9];
    const float* pd0    = (const float*)d_in[10];
    const float* pd1    = (const float*)d_in[11];
    const float* K      = (const float*)d_in[12];
    const float* Ki     = (const float*)d_in[13];

    float*  coeff   = (float*)d_ws;                   // 2 KB
    float2* partial = (float2*)((char*)d_ws + 2048);  // 2*9600 float2 = 150 KB

    precompute_coeffs<<<1, 64, 0, stream>>>(R0, t0, R1, t1, Ki, coeff);
    dim3 grid(TILES, BB, 2);
    fused_loss<<<grid, TPB, 0, stream>>>(depth0, depth1, flow0, flow1, amb0, amb1,
                                         pd0, pd1, K, coeff, partial);
    finalize_kernel<<<1, 256, 0, stream>>>(partial, (float*)d_out);
}

// Round 4
// 118.265 us; speedup vs baseline: 2.7906x; 1.6549x over previous
//
#include <hip/hip_runtime.h>

#define HH 480
#define WW 640
#define BB 16
constexpr int HW = HH * WW;            // 307200
constexpr int TW = 64, TH = 32;        // output tile per block
constexpr int HALO = 5;
constexpr int RW = TW + 2 * HALO;      // 74
constexpr int RH = TH + 2 * HALO;      // 42
constexpr int RN = RW * RH;            // 3108
constexpr int TPB = 512;               // 8 waves
constexpr int TILES_X = WW / TW;       // 10
constexpr int TILES_Y = HH / TH;       // 15
constexpr int TILES = TILES_X * TILES_Y; // 150

// Per-(dir,batch) coefficients: 16 floats
//  [0..2]  a   : z-row of (M @ Ki), M = R_dst @ R_src^T   (for d1)
//  [3]     cz  : t_dst.z - (M @ t_src).z
//  [4..12] P   : M^T @ Ki   (for uv0 field of dst frame reprojected to src)
//  [13..15] e  : t_src - M^T @ t_dst
__global__ void precompute_coeffs(const float* __restrict__ R0, const float* __restrict__ t0,
                                  const float* __restrict__ R1, const float* __restrict__ t1,
                                  const float* __restrict__ Ki, float* __restrict__ coeff) {
    int tid = threadIdx.x;
    if (tid >= 2 * BB) return;
    int dir = tid >> 4;
    int b = tid & 15;
    const float* Rs = (dir ? R1 : R0) + b * 9;
    const float* Ts = (dir ? t1 : t0) + b * 3;
    const float* Rd = (dir ? R0 : R1) + b * 9;
    const float* Td = (dir ? t0 : t1) + b * 3;

    float M[3][3];
    for (int i = 0; i < 3; i++)
        for (int j = 0; j < 3; j++)
            M[i][j] = Rd[i*3+0]*Rs[j*3+0] + Rd[i*3+1]*Rs[j*3+1] + Rd[i*3+2]*Rs[j*3+2];

    float a[3];
    for (int j = 0; j < 3; j++)
        a[j] = M[2][0]*Ki[0+j] + M[2][1]*Ki[3+j] + M[2][2]*Ki[6+j];
    float cz = Td[2] - (M[2][0]*Ts[0] + M[2][1]*Ts[1] + M[2][2]*Ts[2]);

    float P[9], e[3];
    for (int i = 0; i < 3; i++)
        for (int j = 0; j < 3; j++)
            P[i*3+j] = M[0][i]*Ki[0+j] + M[1][i]*Ki[3+j] + M[2][i]*Ki[6+j];
    for (int i = 0; i < 3; i++)
        e[i] = Ts[i] - (M[0][i]*Td[0] + M[1][i]*Td[1] + M[2][i]*Td[2]);

    float* o = coeff + tid * 16;
    o[0]=a[0]; o[1]=a[1]; o[2]=a[2]; o[3]=cz;
    #pragma unroll
    for (int i = 0; i < 9; i++) o[4+i] = P[i];
    o[13]=e[0]; o[14]=e[1]; o[15]=e[2];
}

__launch_bounds__(TPB)
__global__ void fused_loss2(const float* __restrict__ depth0, const float* __restrict__ depth1,
                            const float* __restrict__ flow0,  const float* __restrict__ flow1,
                            const float* __restrict__ amb0,   const float* __restrict__ amb1,
                            const float* __restrict__ pd0,    const float* __restrict__ pd1,
                            const float* __restrict__ K,
                            const float* __restrict__ coeff,
                            float2* __restrict__ partial) {
    __shared__ float4 c4[RN];    // dst (d, fx, fy, amb)
    __shared__ float  pdl[RN];   // dst pd
    __shared__ float  red[32];

    const int b = blockIdx.y;
    const int tile = blockIdx.x;
    const int tx = tile % TILES_X, ty = tile / TILES_X;
    const int gx0 = tx * TW - HALO, gy0 = ty * TH - HALO;
    const int tid = threadIdx.x, lane = tid & 63, wv = tid >> 6;

    const float K00 = K[0], K01 = K[1], K02 = K[2];
    const float K10 = K[3], K11 = K[4], K12 = K[5];

    #pragma unroll
    for (int dir = 0; dir < 2; dir++) {
        const float* sD = (dir ? depth1 : depth0) + b * HW;
        const float* sF = (dir ? flow1  : flow0 ) + b * 2 * HW;
        const float* sA = (dir ? amb1   : amb0  ) + b * HW;
        const float* pD = (dir ? depth0 : depth1) + b * HW;
        const float* pF = (dir ? flow0  : flow1 ) + b * 2 * HW;
        const float* pA = (dir ? amb0   : amb1  ) + b * HW;
        const float* pP = (dir ? pd0    : pd1   ) + b * HW;

        if (dir) __syncthreads();   // prior phase's LDS reads + red writes done

        // ---- stage dst halo region into LDS (border-replicate clamp) ----
        for (int r = wv; r < RH; r += 8) {
            const int gy = min(max(gy0 + r, 0), HH - 1);
            const int rowb = gy * WW;
            #pragma unroll
            for (int s = 0; s < 2; s++) {
                const int c = lane + s * 64;
                if (c < RW) {
                    const int gx = min(max(gx0 + c, 0), WW - 1);
                    const int g = rowb + gx;
                    c4[r * RW + c] = make_float4(pD[g], pF[g], pF[HW + g], pA[g]);
                    pdl[r * RW + c] = pP[g];
                }
            }
        }
        __syncthreads();

        const float* cf = coeff + (dir * BB + b) * 16;
        const float a0=cf[0], a1=cf[1], a2=cf[2], cz=cf[3];
        const float P00=cf[4], P01=cf[5], P02=cf[6];
        const float P10=cf[7], P11=cf[8], P12=cf[9];
        const float P20=cf[10], P21=cf[11], P22=cf[12];
        const float e0=cf[13], e1=cf[14], e2=cf[15];

        float n_acc = 0.f, d_acc = 0.f;

        auto corner = [&](float4 c, float pdv, float w, float Lx, float Ly, float Lz,
                          float& s_d, float& s_fx, float& s_fy, float& s_a,
                          float& s_u, float& s_v) {
            const float rx = fmaf(pdv, Lx, e0);
            const float ry = fmaf(pdv, Ly, e1);
            const float rz = fmaf(pdv, Lz, e2);
            const float invd = __builtin_amdgcn_rcpf(fmaxf(rz, 0.f) + 1e-12f);
            const float uu = fmaf(K00, rx, fmaf(K01, ry, K02 * rz)) * invd;
            const float vv = fmaf(K10, rx, fmaf(K11, ry, K12 * rz)) * invd;
            s_d  = fmaf(w, c.x, s_d);
            s_fx = fmaf(w, c.y, s_fx);
            s_fy = fmaf(w, c.z, s_fy);
            s_a  = fmaf(w, c.w, s_a);
            s_u  = fmaf(w, uu,  s_u);
            s_v  = fmaf(w, vv,  s_v);
        };

        #pragma unroll
        for (int k = 0; k < 4; k++) {
            const int row = wv + k * 8;            // 0..31
            const int px = tx * TW + lane;
            const int py = ty * TH + row;
            const int pix = py * WW + px;
            const float fpx = (float)px, fpy = (float)py;

            const float dep = sD[pix];
            const float fx = sF[pix], fy = sF[HW + pix];
            const float av = sA[pix];

            const float d1 = dep * (a0 * fpx + a1 * fpy + a2) + cz;

            const float xs = fpx + fx, ys = fpy + fy;   // normalize/denorm cancels
            const float x0f = floorf(xs), y0f = floorf(ys);
            const float wx1 = xs - x0f, wy1 = ys - y0f;
            const float wx0 = 1.f - wx1, wy0 = 1.f - wy1;
            const int x0 = (int)x0f, y0 = (int)y0f;

            const bool vx0 = (unsigned)x0 < (unsigned)WW;
            const bool vx1 = (unsigned)(x0 + 1) < (unsigned)WW;
            const bool vy0 = (unsigned)y0 < (unsigned)HH;
            const bool vy1 = (unsigned)(y0 + 1) < (unsigned)HH;
            const float w00 = (vx0 && vy0) ? wx0 * wy0 : 0.f;
            const float w10 = (vx1 && vy0) ? wx1 * wy0 : 0.f;
            const float w01 = (vx0 && vy1) ? wx0 * wy1 : 0.f;
            const float w11 = (vx1 && vy1) ? wx1 * wy1 : 0.f;

            // linear forms at (x0f,y0f); corners add P-column constants
            const float Lx0 = fmaf(P00, x0f, fmaf(P01, y0f, P02));
            const float Ly0 = fmaf(P10, x0f, fmaf(P11, y0f, P12));
            const float Lz0 = fmaf(P20, x0f, fmaf(P21, y0f, P22));

            float s_d = 0.f, s_fx = 0.f, s_fy = 0.f, s_a = 0.f, s_u = 0.f, s_v = 0.f;

            const int lx0 = x0 - gx0, ly0 = y0 - gy0;
            if ((unsigned)lx0 < (unsigned)(RW - 1) && (unsigned)ly0 < (unsigned)(RH - 1)) {
                const int l0 = ly0 * RW + lx0;
                corner(c4[l0],        pdl[l0],        w00, Lx0,       Ly0,       Lz0,
                       s_d, s_fx, s_fy, s_a, s_u, s_v);
                corner(c4[l0+1],      pdl[l0+1],      w10, Lx0+P00,   Ly0+P10,   Lz0+P20,
                       s_d, s_fx, s_fy, s_a, s_u, s_v);
                corner(c4[l0+RW],     pdl[l0+RW],     w01, Lx0+P01,   Ly0+P11,   Lz0+P21,
                       s_d, s_fx, s_fy, s_a, s_u, s_v);
                corner(c4[l0+RW+1],   pdl[l0+RW+1],   w11, Lx0+P00+P01, Ly0+P10+P11, Lz0+P20+P21,
                       s_d, s_fx, s_fy, s_a, s_u, s_v);
            } else {
                // rare: flow beyond halo — exact global fallback
                #pragma unroll
                for (int cy2 = 0; cy2 < 2; cy2++) {
                    #pragma unroll
                    for (int cx2 = 0; cx2 < 2; cx2++) {
                        const int xi = x0 + cx2, yi = y0 + cy2;
                        const bool valid = ((unsigned)xi < (unsigned)WW) &&
                                           ((unsigned)yi < (unsigned)HH);
                        const float w = valid ? (cx2 ? wx1 : wx0) * (cy2 ? wy1 : wy0) : 0.f;
                        float4 c = make_float4(0.f, 0.f, 0.f, 0.f);
                        float pdv = 0.f;
                        if (valid) {
                            const int g = yi * WW + xi;
                            c = make_float4(pD[g], pF[g], pF[HW + g], pA[g]);
                            pdv = pP[g];
                        }
                        corner(c, pdv, w,
                               Lx0 + (cx2 ? P00 : 0.f) + (cy2 ? P01 : 0.f),
                               Ly0 + (cx2 ? P10 : 0.f) + (cy2 ? P11 : 0.f),
                               Lz0 + (cx2 ? P20 : 0.f) + (cy2 ? P21 : 0.f),
                               s_d, s_fx, s_fy, s_a, s_u, s_v);
                    }
                }
            }

            const float diff = fabsf(d1 - s_d);
            const float sfx = fx + s_fx, sfy = fy + s_fy;
            const bool fb = (sfx * sfx + sfy * sfy) <
                            (0.5f + 0.02f * ((fx * fx + fy * fy) + (s_fx * s_fx + s_fy * s_fy)));
            const bool vc = fabsf(av - s_a) < 0.01f;
            const float du = s_u - fpx, dv = s_v - fpy;
            const bool rf = (du * du + dv * dv) < 1.f;
            const float m = (fb && vc && rf) ? 1.f : 0.f;
            n_acc = fmaf(diff, m, n_acc);
            d_acc += m;
        }

        #pragma unroll
        for (int off = 32; off > 0; off >>= 1) {
            n_acc += __shfl_down(n_acc, off);
            d_acc += __shfl_down(d_acc, off);
        }
        if (lane == 0) { red[dir * 16 + wv] = n_acc; red[dir * 16 + 8 + wv] = d_acc; }
    }

    __syncthreads();
    if (tid == 0) {
        float N0 = 0.f, D0 = 0.f, N1 = 0.f, D1 = 0.f;
        #pragma unroll
        for (int i = 0; i < 8; i++) {
            N0 += red[i];      D0 += red[8 + i];
            N1 += red[16 + i]; D1 += red[24 + i];
        }
        partial[b * TILES + tile] = make_float2(N0, D0);
        partial[BB * TILES + b * TILES + tile] = make_float2(N1, D1);
    }
}

__global__ void finalize_kernel(const float2* __restrict__ partial, float* __restrict__ out) {
    const int NPB = BB * TILES; // 2400 per direction
    double n0 = 0, d0 = 0, n1 = 0, d1 = 0;
    for (int i = threadIdx.x; i < NPB; i += 256) {
        float2 p = partial[i];        n0 += p.x; d0 += p.y;
        float2 q = partial[NPB + i];  n1 += q.x; d1 += q.y;
    }
    #pragma unroll
    for (int off = 32; off > 0; off >>= 1) {
        n0 += __shfl_down(n0, off); d0 += __shfl_down(d0, off);
        n1 += __shfl_down(n1, off); d1 += __shfl_down(d1, off);
    }
    __shared__ double red[16];
    int wave = threadIdx.x >> 6, lane = threadIdx.x & 63;
    if (lane == 0) { red[wave] = n0; red[4+wave] = d0; red[8+wave] = n1; red[12+wave] = d1; }
    __syncthreads();
    if (threadIdx.x == 0) {
        double N0 = red[0]+red[1]+red[2]+red[3];
        double D0 = red[4]+red[5]+red[6]+red[7];
        double N1 = red[8]+red[9]+red[10]+red[11];
        double D1 = red[12]+red[13]+red[14]+red[15];
        out[0] = (float)(N0 / (D0 + 1e-8) + N1 / (D1 + 1e-8));
    }
}

extern "C" void kernel_launch(void* const* d_in, const int* in_sizes, int n_in,
                              void* d_out, int out_size, void* d_ws, size_t ws_size,
                              hipStream_t stream) {
    const float* depth0 = (const float*)d_in[0];
    const float* depth1 = (const float*)d_in[1];
    const float* R0     = (const float*)d_in[2];
    const float* t0     = (const float*)d_in[3];
    const float* R1     = (const float*)d_in[4];
    const float* t1     = (const float*)d_in[5];
    const float* flow0  = (const float*)d_in[6];
    const float* flow1  = (const float*)d_in[7];
    const float* amb0   = (const float*)d_in[8];
    const float* amb1   = (const float*)d_in[9];
    const float* pd0    = (const float*)d_in[10];
    const float* pd1    = (const float*)d_in[11];
    const float* K      = (const float*)d_in[12];
    const float* Ki     = (const float*)d_in[13];

    float*  coeff   = (float*)d_ws;                   // 2 KB
    float2* partial = (float2*)((char*)d_ws + 2048);  // 2*2400 float2 = 38.4 KB

    precompute_coeffs<<<1, 64, 0, stream>>>(R0, t0, R1, t1, Ki, coeff);
    dim3 grid(TILES, BB, 1);
    fused_loss2<<<grid, TPB, 0, stream>>>(depth0, depth1, flow0, flow1, amb0, amb1,
                                          pd0, pd1, K, coeff, partial);
    finalize_kernel<<<1, 256, 0, stream>>>(partial, (float*)d_out);
}

// Round 5
// 98.791 us; speedup vs baseline: 3.3406x; 1.1971x over previous
//
#include <hip/hip_runtime.h>

#define HH 480
#define WW 640
#define BB 16
constexpr int HW = HH * WW;            // 307200
constexpr int TW = 64, TH = 16;        // output tile per block
constexpr int HALO = 5;
constexpr int RW = TW + 2 * HALO;      // 74
constexpr int RH = TH + 2 * HALO;      // 26
constexpr int RN = RW * RH;            // 1924
constexpr int TPB = 512;               // 8 waves
constexpr int TILES_X = WW / TW;       // 10
constexpr int TILES_Y = HH / TH;       // 30
constexpr int TILES = TILES_X * TILES_Y; // 300

// Per-(dir,batch) coefficients: 16 floats
//  [0..2]  a   : z-row of (M @ Ki), M = R_dst @ R_src^T   (for d1)
//  [3]     cz  : t_dst.z - (M @ t_src).z
//  [4..12] P   : M^T @ Ki   (for uv0 field of dst frame reprojected to src)
//  [13..15] e  : t_src - M^T @ t_dst
__global__ void precompute_coeffs(const float* __restrict__ R0, const float* __restrict__ t0,
                                  const float* __restrict__ R1, const float* __restrict__ t1,
                                  const float* __restrict__ Ki, float* __restrict__ coeff) {
    int tid = threadIdx.x;
    if (tid >= 2 * BB) return;
    int dir = tid >> 4;
    int b = tid & 15;
    const float* Rs = (dir ? R1 : R0) + b * 9;
    const float* Ts = (dir ? t1 : t0) + b * 3;
    const float* Rd = (dir ? R0 : R1) + b * 9;
    const float* Td = (dir ? t0 : t1) + b * 3;

    float M[3][3];
    for (int i = 0; i < 3; i++)
        for (int j = 0; j < 3; j++)
            M[i][j] = Rd[i*3+0]*Rs[j*3+0] + Rd[i*3+1]*Rs[j*3+1] + Rd[i*3+2]*Rs[j*3+2];

    float a[3];
    for (int j = 0; j < 3; j++)
        a[j] = M[2][0]*Ki[0+j] + M[2][1]*Ki[3+j] + M[2][2]*Ki[6+j];
    float cz = Td[2] - (M[2][0]*Ts[0] + M[2][1]*Ts[1] + M[2][2]*Ts[2]);

    float P[9], e[3];
    for (int i = 0; i < 3; i++)
        for (int j = 0; j < 3; j++)
            P[i*3+j] = M[0][i]*Ki[0+j] + M[1][i]*Ki[3+j] + M[2][i]*Ki[6+j];
    for (int i = 0; i < 3; i++)
        e[i] = Ts[i] - (M[0][i]*Td[0] + M[1][i]*Td[1] + M[2][i]*Td[2]);

    float* o = coeff + tid * 16;
    o[0]=a[0]; o[1]=a[1]; o[2]=a[2]; o[3]=cz;
    #pragma unroll
    for (int i = 0; i < 9; i++) o[4+i] = P[i];
    o[13]=e[0]; o[14]=e[1]; o[15]=e[2];
}

__launch_bounds__(TPB, 8)
__global__ void fused_loss3(const float* __restrict__ depth0, const float* __restrict__ depth1,
                            const float* __restrict__ flow0,  const float* __restrict__ flow1,
                            const float* __restrict__ amb0,   const float* __restrict__ amb1,
                            const float* __restrict__ pd0,    const float* __restrict__ pd1,
                            const float* __restrict__ K,
                            const float* __restrict__ coeff,
                            float2* __restrict__ partial) {
    __shared__ float4 c4[RN];    // dst (d, fx, fy, amb)
    __shared__ float  pdl[RN];   // dst pd
    __shared__ float  red[32];

    // XCD-aware swizzle: consecutive dispatch ids round-robin XCDs; give each
    // XCD a contiguous chunk of (b, tile) so halo-sharing neighbor tiles
    // co-reside in one L2. 4800 % 8 == 0 -> bijective.
    const int fid = blockIdx.y * TILES + blockIdx.x;
    const int nid = (fid & 7) * (TILES * BB / 8) + (fid >> 3);
    const int b = nid / TILES;
    const int tile = nid - b * TILES;

    const int tx = tile % TILES_X, ty = tile / TILES_X;
    const int gx0 = tx * TW - HALO, gy0 = ty * TH - HALO;
    const int tid = threadIdx.x, lane = tid & 63, wv = tid >> 6;
    const bool interior = (tx > 0) && (tx < TILES_X - 1) && (ty > 0) && (ty < TILES_Y - 1);

    const float K00 = K[0], K01 = K[1], K02 = K[2];
    const float K10 = K[3], K11 = K[4], K12 = K[5];

    #pragma unroll
    for (int dir = 0; dir < 2; dir++) {
        const float* sD = (dir ? depth1 : depth0) + b * HW;
        const float* sF = (dir ? flow1  : flow0 ) + b * 2 * HW;
        const float* sA = (dir ? amb1   : amb0  ) + b * HW;
        const float* pD = (dir ? depth0 : depth1) + b * HW;
        const float* pF = (dir ? flow0  : flow1 ) + b * 2 * HW;
        const float* pA = (dir ? amb0   : amb1  ) + b * HW;
        const float* pP = (dir ? pd0    : pd1   ) + b * HW;

        if (dir) __syncthreads();   // prior phase's LDS reads + red writes done

        // ---- stage dst halo region into LDS (border-replicate clamp) ----
        for (int r = wv; r < RH; r += 8) {
            const int gy = min(max(gy0 + r, 0), HH - 1);
            const int rowb = gy * WW;
            #pragma unroll
            for (int s = 0; s < 2; s++) {
                const int c = lane + s * 64;
                if (c < RW) {
                    const int gx = min(max(gx0 + c, 0), WW - 1);
                    const int g = rowb + gx;
                    c4[r * RW + c] = make_float4(pD[g], pF[g], pF[HW + g], pA[g]);
                    pdl[r * RW + c] = pP[g];
                }
            }
        }
        __syncthreads();

        const float* cf = coeff + (dir * BB + b) * 16;
        const float a0=cf[0], a1=cf[1], a2=cf[2], cz=cf[3];
        const float P00=cf[4], P01=cf[5], P02=cf[6];
        const float P10=cf[7], P11=cf[8], P12=cf[9];
        const float P20=cf[10], P21=cf[11], P22=cf[12];
        const float e0=cf[13], e1=cf[14], e2=cf[15];

        float n_acc = 0.f, d_acc = 0.f;

        auto corner = [&](float4 c, float pdv, float w, float Lx, float Ly, float Lz,
                          float& s_d, float& s_fx, float& s_fy, float& s_a,
                          float& s_u, float& s_v) {
            const float rx = fmaf(pdv, Lx, e0);
            const float ry = fmaf(pdv, Ly, e1);
            const float rz = fmaf(pdv, Lz, e2);
            const float invd = __builtin_amdgcn_rcpf(fmaxf(rz, 0.f) + 1e-12f);
            const float uu = fmaf(K00, rx, fmaf(K01, ry, K02 * rz)) * invd;
            const float vv = fmaf(K10, rx, fmaf(K11, ry, K12 * rz)) * invd;
            s_d  = fmaf(w, c.x, s_d);
            s_fx = fmaf(w, c.y, s_fx);
            s_fy = fmaf(w, c.z, s_fy);
            s_a  = fmaf(w, c.w, s_a);
            s_u  = fmaf(w, uu,  s_u);
            s_v  = fmaf(w, vv,  s_v);
        };

        #pragma unroll
        for (int k = 0; k < 2; k++) {
            const int row = wv + k * 8;            // 0..15
            const int px = tx * TW + lane;
            const int py = ty * TH + row;
            const int pix = py * WW + px;
            const float fpx = (float)px, fpy = (float)py;

            const float dep = sD[pix];
            const float fx = sF[pix], fy = sF[HW + pix];
            const float av = sA[pix];

            const float d1 = dep * (a0 * fpx + a1 * fpy + a2) + cz;

            const float xs = fpx + fx, ys = fpy + fy;   // normalize/denorm cancels
            const float x0f = floorf(xs), y0f = floorf(ys);
            const float wx1 = xs - x0f, wy1 = ys - y0f;
            const float wx0 = 1.f - wx1, wy0 = 1.f - wy1;
            const int x0 = (int)x0f, y0 = (int)y0f;

            float w00, w10, w01, w11;
            if (interior) {
                // >=16 px from the image border; flow escaping is P(|z|>8)~0
                w00 = wx0 * wy0; w10 = wx1 * wy0; w01 = wx0 * wy1; w11 = wx1 * wy1;
            } else {
                const bool vx0 = (unsigned)x0 < (unsigned)WW;
                const bool vx1 = (unsigned)(x0 + 1) < (unsigned)WW;
                const bool vy0 = (unsigned)y0 < (unsigned)HH;
                const bool vy1 = (unsigned)(y0 + 1) < (unsigned)HH;
                w00 = (vx0 && vy0) ? wx0 * wy0 : 0.f;
                w10 = (vx1 && vy0) ? wx1 * wy0 : 0.f;
                w01 = (vx0 && vy1) ? wx0 * wy1 : 0.f;
                w11 = (vx1 && vy1) ? wx1 * wy1 : 0.f;
            }

            // linear forms at (x0f,y0f); corners add P-column constants
            const float Lx0 = fmaf(P00, x0f, fmaf(P01, y0f, P02));
            const float Ly0 = fmaf(P10, x0f, fmaf(P11, y0f, P12));
            const float Lz0 = fmaf(P20, x0f, fmaf(P21, y0f, P22));

            float s_d = 0.f, s_fx = 0.f, s_fy = 0.f, s_a = 0.f, s_u = 0.f, s_v = 0.f;

            const int lx0 = x0 - gx0, ly0 = y0 - gy0;
            if ((unsigned)lx0 < (unsigned)(RW - 1) && (unsigned)ly0 < (unsigned)(RH - 1)) {
                const int l0 = ly0 * RW + lx0;
                corner(c4[l0],        pdl[l0],        w00, Lx0,       Ly0,       Lz0,
                       s_d, s_fx, s_fy, s_a, s_u, s_v);
                corner(c4[l0+1],      pdl[l0+1],      w10, Lx0+P00,   Ly0+P10,   Lz0+P20,
                       s_d, s_fx, s_fy, s_a, s_u, s_v);
                corner(c4[l0+RW],     pdl[l0+RW],     w01, Lx0+P01,   Ly0+P11,   Lz0+P21,
                       s_d, s_fx, s_fy, s_a, s_u, s_v);
                corner(c4[l0+RW+1],   pdl[l0+RW+1],   w11, Lx0+P00+P01, Ly0+P10+P11, Lz0+P20+P21,
                       s_d, s_fx, s_fy, s_a, s_u, s_v);
            } else {
                // rare: flow beyond halo — exact global fallback
                #pragma unroll
                for (int cy2 = 0; cy2 < 2; cy2++) {
                    #pragma unroll
                    for (int cx2 = 0; cx2 < 2; cx2++) {
                        const int xi = x0 + cx2, yi = y0 + cy2;
                        const bool valid = ((unsigned)xi < (unsigned)WW) &&
                                           ((unsigned)yi < (unsigned)HH);
                        const float w = valid ? (cx2 ? wx1 : wx0) * (cy2 ? wy1 : wy0) : 0.f;
                        float4 c = make_float4(0.f, 0.f, 0.f, 0.f);
                        float pdv = 0.f;
                        if (valid) {
                            const int g = yi * WW + xi;
                            c = make_float4(pD[g], pF[g], pF[HW + g], pA[g]);
                            pdv = pP[g];
                        }
                        corner(c, pdv, w,
                               Lx0 + (cx2 ? P00 : 0.f) + (cy2 ? P01 : 0.f),
                               Ly0 + (cx2 ? P10 : 0.f) + (cy2 ? P11 : 0.f),
                               Lz0 + (cx2 ? P20 : 0.f) + (cy2 ? P21 : 0.f),
                               s_d, s_fx, s_fy, s_a, s_u, s_v);
                    }
                }
            }

            const float diff = fabsf(d1 - s_d);
            const float sfx = fx + s_fx, sfy = fy + s_fy;
            const bool fb = (sfx * sfx + sfy * sfy) <
                            (0.5f + 0.02f * ((fx * fx + fy * fy) + (s_fx * s_fx + s_fy * s_fy)));
            const bool vc = fabsf(av - s_a) < 0.01f;
            const float du = s_u - fpx, dv = s_v - fpy;
            const bool rf = (du * du + dv * dv) < 1.f;
            const float m = (fb && vc && rf) ? 1.f : 0.f;
            n_acc = fmaf(diff, m, n_acc);
            d_acc += m;
        }

        #pragma unroll
        for (int off = 32; off > 0; off >>= 1) {
            n_acc += __shfl_down(n_acc, off);
            d_acc += __shfl_down(d_acc, off);
        }
        if (lane == 0) { red[dir * 16 + wv] = n_acc; red[dir * 16 + 8 + wv] = d_acc; }
    }

    __syncthreads();
    if (tid == 0) {
        float N0 = 0.f, D0 = 0.f, N1 = 0.f, D1 = 0.f;
        #pragma unroll
        for (int i = 0; i < 8; i++) {
            N0 += red[i];      D0 += red[8 + i];
            N1 += red[16 + i]; D1 += red[24 + i];
        }
        partial[b * TILES + tile] = make_float2(N0, D0);
        partial[BB * TILES + b * TILES + tile] = make_float2(N1, D1);
    }
}

__global__ void finalize_kernel(const float2* __restrict__ partial, float* __restrict__ out) {
    const int NPB = BB * TILES; // 4800 per direction
    double n0 = 0, d0 = 0, n1 = 0, d1 = 0;
    for (int i = threadIdx.x; i < NPB; i += 256) {
        float2 p = partial[i];        n0 += p.x; d0 += p.y;
        float2 q = partial[NPB + i];  n1 += q.x; d1 += q.y;
    }
    #pragma unroll
    for (int off = 32; off > 0; off >>= 1) {
        n0 += __shfl_down(n0, off); d0 += __shfl_down(d0, off);
        n1 += __shfl_down(n1, off); d1 += __shfl_down(d1, off);
    }
    __shared__ double red[16];
    int wave = threadIdx.x >> 6, lane = threadIdx.x & 63;
    if (lane == 0) { red[wave] = n0; red[4+wave] = d0; red[8+wave] = n1; red[12+wave] = d1; }
    __syncthreads();
    if (threadIdx.x == 0) {
        double N0 = red[0]+red[1]+red[2]+red[3];
        double D0 = red[4]+red[5]+red[6]+red[7];
        double N1 = red[8]+red[9]+red[10]+red[11];
        double D1 = red[12]+red[13]+red[14]+red[15];
        out[0] = (float)(N0 / (D0 + 1e-8) + N1 / (D1 + 1e-8));
    }
}

extern "C" void kernel_launch(void* const* d_in, const int* in_sizes, int n_in,
                              void* d_out, int out_size, void* d_ws, size_t ws_size,
                              hipStream_t stream) {
    const float* depth0 = (const float*)d_in[0];
    const float* depth1 = (const float*)d_in[1];
    const float* R0     = (const float*)d_in[2];
    const float* t0     = (const float*)d_in[3];
    const float* R1     = (const float*)d_in[4];
    const float* t1     = (const float*)d_in[5];
    const float* flow0  = (const float*)d_in[6];
    const float* flow1  = (const float*)d_in[7];
    const float* amb0   = (const float*)d_in[8];
    const float* amb1   = (const float*)d_in[9];
    const float* pd0    = (const float*)d_in[10];
    const float* pd1    = (const float*)d_in[11];
    const float* K      = (const float*)d_in[12];
    const float* Ki     = (const float*)d_in[13];

    float*  coeff   = (float*)d_ws;                   // 2 KB
    float2* partial = (float2*)((char*)d_ws + 2048);  // 2*4800 float2 = 76.8 KB

    precompute_coeffs<<<1, 64, 0, stream>>>(R0, t0, R1, t1, Ki, coeff);
    dim3 grid(TILES, BB, 1);
    fused_loss3<<<grid, TPB, 0, stream>>>(depth0, depth1, flow0, flow1, amb0, amb1,
                                          pd0, pd1, K, coeff, partial);
    finalize_kernel<<<1, 256, 0, stream>>>(partial, (float*)d_out);
}